// Round 7
// baseline (163.888 us; speedup 1.0000x reference)
//
#include <hip/hip_runtime.h>
#include <hip/hip_bf16.h>
#include <math.h>

#define VOCAB 100000
#define EMBED 128
#define BATCH 16384
#define NPOS 10
#define NNEG 50
#define NLAB 60
#define NSLICE 8
#define SLICE_ROWS (VOCAB / NSLICE)    // 12500 rows -> 3.2 MB bf16, fits 4 MB XCD L2
#define CAP 131072                     // per-bucket entry capacity (mean 122880, sigma~330)

// ---- ws layout (bytes); all offsets 16B-aligned ----
#define WS_TABLE   0u                              // 100000*128*2 = 25,600,000
#define WS_CBUF    25600000u                       // 16384*128*2  =  4,194,304
#define WS_BSLOT   (WS_CBUF + 4194304u)            // 8*131072*4   =  4,194,304
#define WS_LAB     (WS_BSLOT + 4194304u)           // 8*131072*4   =  4,194,304
#define WS_COUNTS  (WS_LAB + 4194304u)             // 32
#define WS_NEED    (WS_COUNTS + 64u)

// ---------- helpers ----------
__device__ __forceinline__ float fast_log_sigmoid(float x) {
    const float e = __expf(-fabsf(x));
    return fminf(x, 0.0f) - __logf(1.0f + e);
}
__device__ __forceinline__ float dot4(float4 a, float4 b) {
    return fmaf(a.x, b.x, fmaf(a.y, b.y, fmaf(a.z, b.z, a.w * b.w)));
}
// f32 -> bf16 bits, RNE (finite inputs)
__device__ __forceinline__ unsigned bf16rne(float f) {
    unsigned u = __float_as_uint(f);
    return (u + 0x7fffu + ((u >> 16) & 1u)) >> 16;
}
__device__ __forceinline__ unsigned pack2(float lo, float hi) {
    return bf16rne(lo) | (bf16rne(hi) << 16);
}
__device__ __forceinline__ float bl(unsigned u) { return __uint_as_float(u << 16); }
__device__ __forceinline__ float bh(unsigned u) { return __uint_as_float(u & 0xffff0000u); }
// dot of 8 bf16 pairs (both operands packed bf16)
__device__ __forceinline__ float dot8bb(uint4 a, uint4 b) {
    float acc =      bl(a.x) * bl(b.x);
    acc = fmaf(bh(a.x), bh(b.x), acc);
    acc = fmaf(bl(a.y), bl(b.y), acc);
    acc = fmaf(bh(a.y), bh(b.y), acc);
    acc = fmaf(bl(a.z), bl(b.z), acc);
    acc = fmaf(bh(a.z), bh(b.z), acc);
    acc = fmaf(bl(a.w), bl(b.w), acc);
    acc = fmaf(bh(a.w), bh(b.w), acc);
    return acc;
}
// dot8: f32 center halves vs packed bf16
__device__ __forceinline__ float dot8(float4 x, float4 y, uint4 v) {
    float acc =      x.x * bl(v.x);
    acc = fmaf(x.y, bh(v.x), acc);
    acc = fmaf(x.z, bl(v.y), acc);
    acc = fmaf(x.w, bh(v.y), acc);
    acc = fmaf(y.x, bl(v.z), acc);
    acc = fmaf(y.y, bh(v.z), acc);
    acc = fmaf(y.z, bl(v.w), acc);
    acc = fmaf(y.w, bh(v.w), acc);
    return acc;
}

// ---------- pass 0: zero out[] and counts[] ----------
__global__ __launch_bounds__(256) void zero_kernel(float* __restrict__ out,
                                                   unsigned* __restrict__ counts) {
    const int i = blockIdx.x * 256 + threadIdx.x;
    if (i < BATCH) out[i] = 0.0f;
    if (i < NSLICE) counts[i] = 0u;
}

// ---------- pass 1: out_embed f32 -> packed bf16 table ----------
__global__ __launch_bounds__(256) void cvt_bf16_kernel(
    const float* __restrict__ src, unsigned* __restrict__ dst, int n8)
{
    int i = blockIdx.x * 256 + threadIdx.x;
    const int stride = gridDim.x * 256;
    const float4* __restrict__ s4 = reinterpret_cast<const float4*>(src);
    uint4* __restrict__ d4 = reinterpret_cast<uint4*>(dst);
    for (; i < n8; i += stride) {
        const float4 a = s4[2 * i];
        const float4 b = s4[2 * i + 1];
        uint4 o;
        o.x = pack2(a.x, a.y);
        o.y = pack2(a.z, a.w);
        o.z = pack2(b.x, b.y);
        o.w = pack2(b.z, b.w);
        d4[i] = o;
    }
}

// ---------- pass 2: compact center rows -> cbuf bf16 [BATCH][64 uints] ----------
__global__ __launch_bounds__(256) void cbuf_kernel(
    const int* __restrict__ input_labels, const float* __restrict__ in_embed,
    unsigned* __restrict__ cbuf)
{
    const int gid = blockIdx.x * 256 + threadIdx.x;   // 0 .. BATCH*32
    const int b = gid >> 5, part = gid & 31;
    const float4 v = *reinterpret_cast<const float4*>(
        in_embed + (unsigned)input_labels[b] * EMBED + part * 4);
    uint2 o;
    o.x = pack2(v.x, v.y);
    o.y = pack2(v.z, v.w);
    *reinterpret_cast<uint2*>(cbuf + b * 64 + part * 2) = o;
}

// ---------- pass 3: bucket (b,slot,label) by vocab slice ----------
__global__ __launch_bounds__(256) void bucket_kernel(
    const int* __restrict__ pos_labels, const int* __restrict__ neg_labels,
    unsigned* __restrict__ ebslot, unsigned* __restrict__ elab,
    unsigned* __restrict__ counts)
{
    __shared__ unsigned cnt[NSLICE], base[NSLICE], cur[NSLICE];
    const int tid = threadIdx.x;
    const int b0 = blockIdx.x * 64;                   // 64 b's per block
    if (tid < NSLICE) { cnt[tid] = 0u; cur[tid] = 0u; }
    __syncthreads();
    for (int e = tid; e < 64 * NLAB; e += 256) {
        const int q = e / NLAB, slot = e - q * NLAB;
        const int b = b0 + q;
        const int label = (slot < NPOS) ? pos_labels[b * NPOS + slot]
                                        : neg_labels[b * NNEG + (slot - NPOS)];
        atomicAdd(&cnt[label / SLICE_ROWS], 1u);
    }
    __syncthreads();
    if (tid < NSLICE) base[tid] = atomicAdd(&counts[tid], cnt[tid]);
    __syncthreads();
    for (int e = tid; e < 64 * NLAB; e += 256) {
        const int q = e / NLAB, slot = e - q * NLAB;
        const int b = b0 + q;
        const int label = (slot < NPOS) ? pos_labels[b * NPOS + slot]
                                        : neg_labels[b * NNEG + (slot - NPOS)];
        const int s = label / SLICE_ROWS;
        const unsigned pos = base[s] + atomicAdd(&cur[s], 1u);
        if (pos < CAP) {
            ebslot[s * CAP + pos] = ((unsigned)b << 6) | (unsigned)slot;
            elab[s * CAP + pos]   = (unsigned)label;
        }
    }
}

// ---------- pass 4: slice-local dot + log-sigmoid, atomic accumulate ----------
__global__ __launch_bounds__(256) void main_kernel(
    const unsigned* __restrict__ ebslot, const unsigned* __restrict__ elab,
    const unsigned* __restrict__ counts, const unsigned* __restrict__ table,
    const unsigned* __restrict__ cbuf, float* __restrict__ out)
{
    const int s = blockIdx.x & 7;          // bid%8 -> XCD s (round-robin dispatch)
    const int j = blockIdx.x >> 3;         // 0..255 within bucket
    const int wave = threadIdx.x >> 6;
    const int lane = threadIdx.x & 63;
    const int g = lane >> 3, t = lane & 7;

    unsigned count = counts[s];
    if (count > CAP) count = CAP;
    const unsigned* __restrict__ bsl = ebslot + s * CAP;
    const unsigned* __restrict__ lb  = elab + s * CAP;

    for (unsigned i0 = (unsigned)j * 32u; i0 < count; i0 += 256u * 32u) {
        const unsigned wbase = i0 + (unsigned)wave * 8u;
        // lanes 0..7 load 8 entries, broadcast to groups
        unsigned my_bslot = 0u, my_lab = 0u;
        const unsigned li = wbase + (unsigned)lane;
        if (lane < 8 && li < count) { my_bslot = bsl[li]; my_lab = lb[li]; }
        const unsigned ebs = __shfl(my_bslot, g);
        const unsigned el  = __shfl(my_lab,  g);
        const bool valid = (wbase + (unsigned)g) < count;
        const int b    = (int)(ebs >> 6);
        const int slot = (int)(ebs & 63u);

        float acc = 0.0f;
        if (valid) {
            const unsigned co = (unsigned)b * 64u + (unsigned)(t * 4);
            const uint4 c0 = *reinterpret_cast<const uint4*>(cbuf + co);
            const uint4 c1 = *reinterpret_cast<const uint4*>(cbuf + co + 32);
            const unsigned ro = el * 64u + (unsigned)(t * 4);
            const uint4 r0 = *reinterpret_cast<const uint4*>(table + ro);
            const uint4 r1 = *reinterpret_cast<const uint4*>(table + ro + 32);
            acc = dot8bb(c0, r0) + dot8bb(c1, r1);
        }
        acc += __shfl_xor(acc, 1);
        acc += __shfl_xor(acc, 2);
        acc += __shfl_xor(acc, 4);

        if (t == 0 && valid) {
            const float w = (slot < NPOS) ? -1.0f : 1.0f;   // out = log_neg - log_pos
            atomicAdd(&out[b], w * fast_log_sigmoid(acc));
        }
    }
}

// ---------- fallback: round-6 gather (bf16 table only) ----------
__global__ __launch_bounds__(256) void skipgram_loss_bf16_kernel(
    const int* __restrict__ input_labels,
    const int* __restrict__ pos_labels,
    const int* __restrict__ neg_labels,
    const float* __restrict__ in_embed,
    const unsigned* __restrict__ out_bf,
    float* __restrict__ out)
{
    const int wave = threadIdx.x >> 6;
    const int lane = threadIdx.x & 63;
    const int b = blockIdx.x * 4 + wave;
    const int g = lane >> 3, t = lane & 7;

    const float* __restrict__ crow = in_embed + (unsigned)input_labels[b] * EMBED;
    const float4 ca = *reinterpret_cast<const float4*>(crow + t * 8);
    const float4 cb = *reinterpret_cast<const float4*>(crow + t * 8 + 4);
    const float4 cc = *reinterpret_cast<const float4*>(crow + 64 + t * 8);
    const float4 cd = *reinterpret_cast<const float4*>(crow + 64 + t * 8 + 4);

    int lab;
    if (lane < NPOS)       lab = pos_labels[b * NPOS + lane];
    else if (lane < NLAB)  lab = neg_labels[b * NNEG + (lane - NPOS)];
    else                   lab = 0;

    unsigned roff[8];
    #pragma unroll
    for (int p = 0; p < 8; ++p)
        roff[p] = (unsigned)__shfl(lab, p * 8 + g) * 64u + (unsigned)(t * 4);

    uint4 u0 = *reinterpret_cast<const uint4*>(out_bf + roff[0]);
    uint4 u1 = *reinterpret_cast<const uint4*>(out_bf + roff[0] + 32);

    float total = 0.0f;
    #pragma unroll
    for (int p = 0; p < 8; ++p) {
        uint4 n0, n1;
        if (p < 7) {
            n0 = *reinterpret_cast<const uint4*>(out_bf + roff[p + 1]);
            n1 = *reinterpret_cast<const uint4*>(out_bf + roff[p + 1] + 32);
        }
        float acc = dot8(ca, cb, u0) + dot8(cc, cd, u1);
        acc += __shfl_xor(acc, 1);
        acc += __shfl_xor(acc, 2);
        acc += __shfl_xor(acc, 4);
        const int lix = p * 8 + g;
        const float wl = (lix < NLAB) ? ((lix < NPOS) ? -1.0f : 1.0f) : 0.0f;
        total += (t == 0) ? wl * fast_log_sigmoid(acc) : 0.0f;
        if (p < 7) { u0 = n0; u1 = n1; }
    }
    total += __shfl_xor(total, 8);
    total += __shfl_xor(total, 16);
    total += __shfl_xor(total, 32);
    if (lane == 0) out[b] = total;
}

extern "C" void kernel_launch(void* const* d_in, const int* in_sizes, int n_in,
                              void* d_out, int out_size, void* d_ws, size_t ws_size,
                              hipStream_t stream) {
    const int*   input_labels = (const int*)d_in[0];
    const int*   pos_labels   = (const int*)d_in[1];
    const int*   neg_labels   = (const int*)d_in[2];
    const float* in_embed     = (const float*)d_in[3];
    const float* out_embed    = (const float*)d_in[4];
    float*       out          = (float*)d_out;

    char* ws = (char*)d_ws;
    const int n8 = VOCAB * EMBED / 8;

    if (ws_size >= WS_NEED) {
        unsigned* table  = (unsigned*)(ws + WS_TABLE);
        unsigned* cbuf   = (unsigned*)(ws + WS_CBUF);
        unsigned* ebslot = (unsigned*)(ws + WS_BSLOT);
        unsigned* elab   = (unsigned*)(ws + WS_LAB);
        unsigned* counts = (unsigned*)(ws + WS_COUNTS);

        zero_kernel<<<(BATCH + 255) / 256, 256, 0, stream>>>(out, counts);
        cvt_bf16_kernel<<<2048, 256, 0, stream>>>(out_embed, table, n8);
        cbuf_kernel<<<BATCH * 32 / 256, 256, 0, stream>>>(input_labels, in_embed, cbuf);
        bucket_kernel<<<BATCH / 64, 256, 0, stream>>>(pos_labels, neg_labels,
                                                      ebslot, elab, counts);
        main_kernel<<<2048, 256, 0, stream>>>(ebslot, elab, counts, table, cbuf, out);
    } else if (ws_size >= (size_t)VOCAB * EMBED * 2) {
        unsigned* table = (unsigned*)ws;
        cvt_bf16_kernel<<<2048, 256, 0, stream>>>(out_embed, table, n8);
        skipgram_loss_bf16_kernel<<<BATCH / 4, 256, 0, stream>>>(
            input_labels, pos_labels, neg_labels, in_embed, table, out);
    }
}

// Round 8
// 71.244 us; speedup vs baseline: 2.3004x; 2.3004x over previous
//
#include <hip/hip_runtime.h>
#include <hip/hip_bf16.h>
#include <math.h>

#define VOCAB 100000
#define EMBED 128
#define BATCH 16384
#define NPOS 10
#define NNEG 50
#define NLAB 60
#define NSLICE 8
#define SLICE_ROWS (VOCAB / NSLICE)    // 12500 rows * 256 B bf16 = 3.2 MB -> fits 4 MB XCD L2

// ---- ws layout (bytes); 16B-aligned ----
#define WS_TABLE  0u                          // 100000*128*2 = 25,600,000
#define WS_CBUF   25600000u                   // 16384*64*4   =  4,194,304 (bf16 centers, 2/uint)
#define WS_SLAB   (WS_CBUF + 4194304u)        // 16384*64*4   =  4,194,304 (slice-sorted entries)
#define WS_OFFS   (WS_SLAB + 4194304u)        // 16384*8      =    131,072 (8 uchar prefixes / b)
#define WS_PART   (WS_OFFS + 131072u)         // 8*16384*4    =    524,288
#define WS_NEED   (WS_PART + 524288u)         // ~34.6 MB

// ---------- helpers ----------
__device__ __forceinline__ float fast_log_sigmoid(float x) {
    const float e = __expf(-fabsf(x));
    return fminf(x, 0.0f) - __logf(1.0f + e);
}
// f32 -> bf16 bits, RNE (finite inputs)
__device__ __forceinline__ unsigned bf16rne(float f) {
    unsigned u = __float_as_uint(f);
    return (u + 0x7fffu + ((u >> 16) & 1u)) >> 16;
}
__device__ __forceinline__ unsigned pack2(float lo, float hi) {
    return bf16rne(lo) | (bf16rne(hi) << 16);
}
__device__ __forceinline__ float bl(unsigned u) { return __uint_as_float(u << 16); }
__device__ __forceinline__ float bh(unsigned u) { return __uint_as_float(u & 0xffff0000u); }
// dot of 8 bf16 pairs (both operands packed bf16, 2 per uint)
__device__ __forceinline__ float dot8bb(uint4 a, uint4 b) {
    float acc =      bl(a.x) * bl(b.x);
    acc = fmaf(bh(a.x), bh(b.x), acc);
    acc = fmaf(bl(a.y), bl(b.y), acc);
    acc = fmaf(bh(a.y), bh(b.y), acc);
    acc = fmaf(bl(a.z), bl(b.z), acc);
    acc = fmaf(bh(a.z), bh(b.z), acc);
    acc = fmaf(bl(a.w), bl(b.w), acc);
    acc = fmaf(bh(a.w), bh(b.w), acc);
    return acc;
}
// f32 center halves vs packed bf16 (fallback kernel)
__device__ __forceinline__ float dot8fb(float4 x, float4 y, uint4 v) {
    float acc =      x.x * bl(v.x);
    acc = fmaf(x.y, bh(v.x), acc);
    acc = fmaf(x.z, bl(v.y), acc);
    acc = fmaf(x.w, bh(v.y), acc);
    acc = fmaf(y.x, bl(v.z), acc);
    acc = fmaf(y.y, bh(v.z), acc);
    acc = fmaf(y.z, bl(v.w), acc);
    acc = fmaf(y.w, bh(v.w), acc);
    return acc;
}

// ---------- pass 1: out_embed f32 -> packed bf16 table ----------
__global__ __launch_bounds__(256) void cvt_bf16_kernel(
    const float* __restrict__ src, unsigned* __restrict__ dst, int n8)
{
    int i = blockIdx.x * 256 + threadIdx.x;
    const int stride = gridDim.x * 256;
    const float4* __restrict__ s4 = reinterpret_cast<const float4*>(src);
    uint4* __restrict__ d4 = reinterpret_cast<uint4*>(dst);
    for (; i < n8; i += stride) {
        const float4 a = s4[2 * i];
        const float4 b = s4[2 * i + 1];
        uint4 o;
        o.x = pack2(a.x, a.y);
        o.y = pack2(a.z, a.w);
        o.z = pack2(b.x, b.y);
        o.w = pack2(b.z, b.w);
        d4[i] = o;
    }
}

// ---------- pass 2: per-b prep — center cvt + slice counting-sort (one wave / b) ----------
__global__ __launch_bounds__(256) void prep_kernel(
    const int* __restrict__ input_labels,
    const int* __restrict__ pos_labels,
    const int* __restrict__ neg_labels,
    const float* __restrict__ in_embed,
    unsigned* __restrict__ cbuf,     // [B][64] packed bf16 centers
    unsigned* __restrict__ slab,     // [B][64] slice-sorted entries (slot<<17)|label
    uint2* __restrict__ offs)        // [B] 8 uchar exclusive prefixes
{
    const int wave = threadIdx.x >> 6;
    const int lane = threadIdx.x & 63;
    const int b = blockIdx.x * 4 + wave;

    // center f32 -> bf16 (lane handles elems 2l, 2l+1)
    const float2 cv = *reinterpret_cast<const float2*>(
        in_embed + (unsigned)input_labels[b] * EMBED + lane * 2);
    cbuf[b * 64 + lane] = pack2(cv.x, cv.y);

    // one label per lane (lanes 60..63 inactive)
    const bool active = lane < NLAB;
    int label = 0;
    if (lane < NPOS)       label = pos_labels[b * NPOS + lane];
    else if (active)       label = neg_labels[b * NNEG + (lane - NPOS)];
    const unsigned s = (unsigned)label / SLICE_ROWS;   // 0..7

    // per-slice ballots -> exclusive prefix + in-slice rank (no atomics)
    unsigned long long bal[NSLICE];
    #pragma unroll
    for (int k = 0; k < NSLICE; ++k)
        bal[k] = __ballot(active && s == (unsigned)k);
    unsigned prefix[NSLICE];
    unsigned run = 0;
    #pragma unroll
    for (int k = 0; k < NSLICE; ++k) { prefix[k] = run; run += (unsigned)__popcll(bal[k]); }

    // select my slice's prefix/ballot with static indexing (avoid scratch)
    unsigned myprefix = 0;
    unsigned long long mybal = 0;
    #pragma unroll
    for (int k = 0; k < NSLICE; ++k)
        if (s == (unsigned)k) { myprefix = prefix[k]; mybal = bal[k]; }
    const unsigned long long lower = (1ull << lane) - 1ull;
    const unsigned rank = myprefix + (unsigned)__popcll(mybal & lower);

    if (active)
        slab[b * 64 + rank] = ((unsigned)lane << 17) | (unsigned)label;

    if (lane == 0) {
        uint2 o;
        o.x = prefix[0] | (prefix[1] << 8) | (prefix[2] << 16) | (prefix[3] << 24);
        o.y = prefix[4] | (prefix[5] << 8) | (prefix[6] << 16) | (prefix[7] << 24);
        offs[b] = o;
    }
}

// ---------- pass 3: slice-local gather (one wave per (b, slice)) ----------
__global__ __launch_bounds__(256) void main_kernel(
    const unsigned* __restrict__ slab,
    const uint2* __restrict__ offs,
    const unsigned* __restrict__ table,
    const unsigned* __restrict__ cbuf,
    float* __restrict__ partials)        // [8][B]
{
    const int wave = threadIdx.x >> 6;
    const int lane = threadIdx.x & 63;
    const int s = blockIdx.x & 7;                 // slice == XCD (round-robin dispatch)
    const int b = (blockIdx.x >> 3) * 4 + wave;
    const int g = lane >> 3, t = lane & 7;

    // entry range for (b, s)
    const uint2 ov = offs[b];
    const unsigned w0 = (s & 4) ? ov.y : ov.x;
    const unsigned start = (w0 >> ((s & 3) * 8)) & 0xffu;
    unsigned end;
    if (s == 7) end = NLAB;
    else {
        const int s1 = s + 1;
        const unsigned w1 = (s1 & 4) ? ov.y : ov.x;
        end = (w1 >> ((s1 & 3) * 8)) & 0xffu;
    }
    const unsigned cnt = end - start;

    // center (wave-uniform, bf16)
    const unsigned co = (unsigned)b * 64u + (unsigned)(t * 4);
    const uint4 c0 = *reinterpret_cast<const uint4*>(cbuf + co);
    const uint4 c1 = *reinterpret_cast<const uint4*>(cbuf + co + 32);

    float total = 0.0f;
    const unsigned base = (unsigned)b * 64u + start;
    for (unsigned e0 = 0; e0 < cnt; e0 += 8) {
        const unsigned e = e0 + (unsigned)g;
        const bool valid = e < cnt;
        const unsigned ent = slab[base + (valid ? e : 0u)];
        const unsigned label = ent & 0x1FFFFu;
        const unsigned slot  = ent >> 17;

        const unsigned ro = label * 64u + (unsigned)(t * 4);
        const uint4 r0 = *reinterpret_cast<const uint4*>(table + ro);
        const uint4 r1 = *reinterpret_cast<const uint4*>(table + ro + 32);
        float acc = dot8bb(c0, r0) + dot8bb(c1, r1);

        acc += __shfl_xor(acc, 1);
        acc += __shfl_xor(acc, 2);
        acc += __shfl_xor(acc, 4);

        if (t == 0 && valid) {
            const float w = (slot < NPOS) ? -1.0f : 1.0f;   // out = log_neg - log_pos
            total += w * fast_log_sigmoid(acc);
        }
    }

    total += __shfl_xor(total, 8);
    total += __shfl_xor(total, 16);
    total += __shfl_xor(total, 32);
    if (lane == 0) partials[s * BATCH + b] = total;
}

// ---------- pass 4: reduce 8 slice partials -> out ----------
__global__ __launch_bounds__(256) void reduce_kernel(
    const float* __restrict__ partials, float* __restrict__ out)
{
    const int b = blockIdx.x * 256 + threadIdx.x;
    float tt = 0.0f;
    #pragma unroll
    for (int s = 0; s < NSLICE; ++s) tt += partials[s * BATCH + b];
    out[b] = tt;
}

// ---------- fallback: round-6 gather (bf16 table only) ----------
__global__ __launch_bounds__(256) void skipgram_loss_bf16_kernel(
    const int* __restrict__ input_labels,
    const int* __restrict__ pos_labels,
    const int* __restrict__ neg_labels,
    const float* __restrict__ in_embed,
    const unsigned* __restrict__ out_bf,
    float* __restrict__ out)
{
    const int wave = threadIdx.x >> 6;
    const int lane = threadIdx.x & 63;
    const int b = blockIdx.x * 4 + wave;
    const int g = lane >> 3, t = lane & 7;

    const float* __restrict__ crow = in_embed + (unsigned)input_labels[b] * EMBED;
    const float4 ca = *reinterpret_cast<const float4*>(crow + t * 8);
    const float4 cb = *reinterpret_cast<const float4*>(crow + t * 8 + 4);
    const float4 cc = *reinterpret_cast<const float4*>(crow + 64 + t * 8);
    const float4 cd = *reinterpret_cast<const float4*>(crow + 64 + t * 8 + 4);

    int lab;
    if (lane < NPOS)       lab = pos_labels[b * NPOS + lane];
    else if (lane < NLAB)  lab = neg_labels[b * NNEG + (lane - NPOS)];
    else                   lab = 0;

    unsigned roff[8];
    #pragma unroll
    for (int p = 0; p < 8; ++p)
        roff[p] = (unsigned)__shfl(lab, p * 8 + g) * 64u + (unsigned)(t * 4);

    uint4 u0 = *reinterpret_cast<const uint4*>(out_bf + roff[0]);
    uint4 u1 = *reinterpret_cast<const uint4*>(out_bf + roff[0] + 32);

    float total = 0.0f;
    #pragma unroll
    for (int p = 0; p < 8; ++p) {
        uint4 n0, n1;
        if (p < 7) {
            n0 = *reinterpret_cast<const uint4*>(out_bf + roff[p + 1]);
            n1 = *reinterpret_cast<const uint4*>(out_bf + roff[p + 1] + 32);
        }
        float acc = dot8fb(ca, cb, u0) + dot8fb(cc, cd, u1);
        acc += __shfl_xor(acc, 1);
        acc += __shfl_xor(acc, 2);
        acc += __shfl_xor(acc, 4);
        const int lix = p * 8 + g;
        const float wl = (lix < NLAB) ? ((lix < NPOS) ? -1.0f : 1.0f) : 0.0f;
        total += (t == 0) ? wl * fast_log_sigmoid(acc) : 0.0f;
        if (p < 7) { u0 = n0; u1 = n1; }
    }
    total += __shfl_xor(total, 8);
    total += __shfl_xor(total, 16);
    total += __shfl_xor(total, 32);
    if (lane == 0) out[b] = total;
}

extern "C" void kernel_launch(void* const* d_in, const int* in_sizes, int n_in,
                              void* d_out, int out_size, void* d_ws, size_t ws_size,
                              hipStream_t stream) {
    const int*   input_labels = (const int*)d_in[0];
    const int*   pos_labels   = (const int*)d_in[1];
    const int*   neg_labels   = (const int*)d_in[2];
    const float* in_embed     = (const float*)d_in[3];
    const float* out_embed    = (const float*)d_in[4];
    float*       out          = (float*)d_out;

    char* ws = (char*)d_ws;
    const int n8 = VOCAB * EMBED / 8;

    if (ws_size >= WS_NEED) {
        unsigned* table = (unsigned*)(ws + WS_TABLE);
        unsigned* cbuf  = (unsigned*)(ws + WS_CBUF);
        unsigned* slab  = (unsigned*)(ws + WS_SLAB);
        uint2*    offs  = (uint2*)(ws + WS_OFFS);
        float*    part  = (float*)(ws + WS_PART);

        cvt_bf16_kernel<<<2048, 256, 0, stream>>>(out_embed, table, n8);
        prep_kernel<<<BATCH / 4, 256, 0, stream>>>(input_labels, pos_labels,
                                                   neg_labels, in_embed,
                                                   cbuf, slab, offs);
        main_kernel<<<(BATCH / 4) * NSLICE, 256, 0, stream>>>(slab, offs, table,
                                                              cbuf, part);
        reduce_kernel<<<BATCH / 256, 256, 0, stream>>>(part, out);
    } else if (ws_size >= (size_t)VOCAB * EMBED * 2) {
        unsigned* table = (unsigned*)ws;
        cvt_bf16_kernel<<<2048, 256, 0, stream>>>(out_embed, table, n8);
        skipgram_loss_bf16_kernel<<<BATCH / 4, 256, 0, stream>>>(
            input_labels, pos_labels, neg_labels, in_embed, table, out);
    }
}